// Round 1
// baseline (257.264 us; speedup 1.0000x reference)
//
#include <hip/hip_runtime.h>
#include <cstdint>

#define D 256
#define NC 32
#define NCLS 10
#define KNN 10
#define NBLK 32
#define SPLIT 8

__device__ __forceinline__ float wave_sum(float v) {
  #pragma unroll
  for (int off = 32; off; off >>= 1) v += __shfl_xor(v, off);
  return v;
}

// ---------------- gram + T1 = C^T W ----------------
// grid: NC blocks x 256 threads (thread == d index)
__global__ __launch_bounds__(256) void k_gram(const float* __restrict__ C,
                                              const float* __restrict__ W,
                                              float* __restrict__ gram,
                                              float* __restrict__ T1) {
  int j = blockIdx.x, t = threadIdx.x;
  float cj = C[t * NC + j];
  float part[NC + NCLS];
  #pragma unroll
  for (int i = 0; i < NC; ++i) part[i] = cj * C[t * NC + i];
  #pragma unroll
  for (int c = 0; c < NCLS; ++c) part[NC + c] = cj * W[t * NCLS + c];
  __shared__ float red[4][NC + NCLS];
  int lane = t & 63, wv = t >> 6;
  #pragma unroll
  for (int r = 0; r < NC + NCLS; ++r) {
    float v = wave_sum(part[r]);
    if (lane == 0) red[wv][r] = v;
  }
  __syncthreads();
  if (t < NC + NCLS) {
    float v = red[0][t] + red[1][t] + red[2][t] + red[3][t];
    if (t < NC) gram[t * NC + j] = v;      // gram[i][j]
    else        T1[j * NCLS + (t - NC)] = v; // T1[j][cls]
  }
}

// ---------------- Gauss-Jordan solve G S = T1, plus L_sparse_2 / norm ----------------
// 1 block x 256 threads
#define AUGW (NC + NCLS)   // 42
__global__ __launch_bounds__(256) void k_solve(const float* __restrict__ gram,
                                               const float* __restrict__ T1,
                                               float* __restrict__ S,
                                               float* __restrict__ out, int bs) {
  __shared__ float aug[NC][AUGW + 2];
  __shared__ float frow[NC];
  __shared__ float pivinv;
  __shared__ float rs[4][2];
  int tid = threadIdx.x;

  for (int e = tid; e < NC * NC; e += 256) aug[e / NC][e % NC] = gram[e];
  for (int e = tid; e < NC * NCLS; e += 256) aug[e / NCLS][NC + e % NCLS] = T1[e];
  __syncthreads();

  // gram stats
  float s_all = 0.f, s_diag = 0.f;
  for (int e = tid; e < NC * NC; e += 256) {
    float g = aug[e / NC][e % NC];
    s_all += g;
    if (e / NC == e % NC) s_diag += g;
  }
  s_all = wave_sum(s_all);
  s_diag = wave_sum(s_diag);
  int lane = tid & 63, wv = tid >> 6;
  if (lane == 0) { rs[wv][0] = s_all; rs[wv][1] = s_diag; }
  __syncthreads();
  if (tid == 0) {
    float a = rs[0][0] + rs[1][0] + rs[2][0] + rs[3][0];
    float dg = rs[0][1] + rs[1][1] + rs[2][1] + rs[3][1];
    out[(size_t)2 * bs * NCLS + 1] = (a - dg) / (float)(NC * NC); // L_sparse_2
    out[(size_t)2 * bs * NCLS + 2] = dg / (float)(NC * NC);       // norm_metrics
  }

  // Gauss-Jordan (no pivoting; gram is diagonally dominant)
  for (int k = 0; k < NC; ++k) {
    __syncthreads();
    if (tid == 0) pivinv = 1.0f / aug[k][k];
    __syncthreads();
    if (tid < AUGW) aug[k][tid] *= pivinv;
    if (tid < NC) frow[tid] = (tid == k) ? 0.f : aug[tid][k];
    __syncthreads();
    for (int e = tid; e < NC * AUGW; e += 256) {
      int i = e / AUGW, c = e % AUGW;
      if (i != k) aug[i][c] -= frow[i] * aug[k][c];
    }
  }
  __syncthreads();
  for (int e = tid; e < NC * NCLS; e += 256) S[e] = aug[e / NCLS][NC + e % NCLS];
}

// ---------------- predictions: orig_pred and y_pred ----------------
// thread-group of SPLIT threads per row; grid = bs*SPLIT/256 blocks
__global__ __launch_bounds__(256) void k_pred(const float* __restrict__ X,
                                              const float* __restrict__ C,
                                              const float* __restrict__ W,
                                              const float* __restrict__ bvec,
                                              const float* __restrict__ S,
                                              float* __restrict__ out, int bs) {
  int t = blockIdx.x * 256 + threadIdx.x;
  int r = t / SPLIT, q = t % SPLIT;
  if (r >= bs) return;
  const float* x = X + (size_t)r * D;
  float a[NC], o[NCLS];
  #pragma unroll
  for (int c = 0; c < NC; ++c) a[c] = 0.f;
  #pragma unroll
  for (int c = 0; c < NCLS; ++c) o[c] = 0.f;

  int d0 = q * (D / SPLIT);
  for (int d = d0; d < d0 + D / SPLIT; d += 4) {
    float4 xv = *reinterpret_cast<const float4*>(x + d);
    #pragma unroll
    for (int dd = 0; dd < 4; ++dd) {
      float xd = (dd == 0) ? xv.x : (dd == 1) ? xv.y : (dd == 2) ? xv.z : xv.w;
      #pragma unroll
      for (int c = 0; c < NC; ++c) a[c] += xd * C[(d + dd) * NC + c];
      #pragma unroll
      for (int c = 0; c < NCLS; ++c) o[c] += xd * W[(d + dd) * NCLS + c];
    }
  }
  #pragma unroll
  for (int off = 1; off < SPLIT; off <<= 1) {
    #pragma unroll
    for (int c = 0; c < NC; ++c) a[c] += __shfl_xor(a[c], off);
    #pragma unroll
    for (int c = 0; c < NCLS; ++c) o[c] += __shfl_xor(o[c], off);
  }
  if (q == 0) {
    #pragma unroll
    for (int cls = 0; cls < NCLS; ++cls) {
      float y = bvec[cls];
      #pragma unroll
      for (int c = 0; c < NC; ++c) y += a[c] * S[c * NCLS + cls];
      out[(size_t)r * NCLS + cls] = o[cls] + bvec[cls];
      out[(size_t)bs * NCLS + (size_t)r * NCLS + cls] = y;
    }
  }
}

// ---------------- key = x2 - 2*xc for all N rows x 32 concepts ----------------
// thread == row; concept reads are wave-uniform (scalarizable)
__global__ __launch_bounds__(256) void k_key(const float* __restrict__ X,
                                             const float* __restrict__ Cc,
                                             float* __restrict__ keyT, int N) {
  int r = blockIdx.x * 256 + threadIdx.x;
  int rc = r < N ? r : N - 1;
  const float4* xv = reinterpret_cast<const float4*>(X + (size_t)rc * D);
  float acc[NC];
  #pragma unroll
  for (int c = 0; c < NC; ++c) acc[c] = 0.f;
  float x2 = 0.f;
  #pragma unroll 2
  for (int d4 = 0; d4 < D / 4; ++d4) {
    float4 x = xv[d4];
    x2 += x.x * x.x + x.y * x.y + x.z * x.z + x.w * x.w;
    const float* crow = Cc + d4 * 4 * NC;
    #pragma unroll
    for (int c = 0; c < NC; ++c) {
      acc[c] += x.x * crow[c] + x.y * crow[NC + c] + x.z * crow[2 * NC + c] + x.w * crow[3 * NC + c];
    }
  }
  if (r < N) {
    #pragma unroll
    for (int c = 0; c < NC; ++c) keyT[(size_t)c * N + r] = x2 - 2.f * acc[c];
  }
}

// ---------------- per-(concept, chunk) exact top-10 ----------------
// grid: dim3(NBLK, NC), 256 threads
__global__ __launch_bounds__(256) void k_topk(const float* __restrict__ keyT,
                                              float* __restrict__ candK,
                                              int* __restrict__ candI, int N) {
  int j = blockIdx.y, blk = blockIdx.x, tid = threadIdx.x;
  const float* key = keyT + (size_t)j * N;
  int per = (N + NBLK - 1) / NBLK;
  int lo = blk * per;
  int hi = lo + per; if (hi > N) hi = N;

  float bk[KNN]; int bi[KNN];
  #pragma unroll
  for (int q = 0; q < KNN; ++q) { bk[q] = 3.4e38f; bi[q] = 0x7fffffff; }

  for (int i = lo + tid; i < hi; i += 256) {
    float v = key[i];
    if (v < bk[KNN - 1] || (v == bk[KNN - 1] && i < bi[KNN - 1])) {
      float cv = v; int ci = i;
      #pragma unroll
      for (int q = 0; q < KNN; ++q) {
        bool take = (cv < bk[q]) || (cv == bk[q] && ci < bi[q]);
        if (take) {
          float tf = bk[q]; bk[q] = cv; cv = tf;
          int ti = bi[q]; bi[q] = ci; ci = ti;
        }
      }
    }
  }

  __shared__ float sk[256 * KNN];
  __shared__ int si[256 * KNN];
  __shared__ float wv_[4]; __shared__ int wi_[4];
  #pragma unroll
  for (int q = 0; q < KNN; ++q) { sk[tid * KNN + q] = bk[q]; si[tid * KNN + q] = bi[q]; }
  __syncthreads();

  int p = 0;
  int lane = tid & 63, wv = tid >> 6;
  for (int rr = 0; rr < KNN; ++rr) {
    float myv = (p < KNN) ? sk[tid * KNN + p] : 3.4e38f;
    int mygi = (p < KNN) ? si[tid * KNN + p] : 0x7fffffff;
    float hv = myv; int hgi = mygi;
    #pragma unroll
    for (int off = 32; off; off >>= 1) {
      float ov = __shfl_xor(hv, off); int oi = __shfl_xor(hgi, off);
      if (ov < hv || (ov == hv && oi < hgi)) { hv = ov; hgi = oi; }
    }
    if (lane == 0) { wv_[wv] = hv; wi_[wv] = hgi; }
    __syncthreads();
    float bv = wv_[0]; int bgi = wi_[0];
    #pragma unroll
    for (int w = 1; w < 4; ++w) {
      if (wv_[w] < bv || (wv_[w] == bv && wi_[w] < bgi)) { bv = wv_[w]; bgi = wi_[w]; }
    }
    if (p < KNN && myv == bv && mygi == bgi) p++;
    if (tid == 0) {
      candK[((size_t)j * NBLK + blk) * KNN + rr] = bv;
      candI[((size_t)j * NBLK + blk) * KNN + rr] = bgi;
    }
    __syncthreads();
  }
}

// ---------------- merge candidates, gather knn, dot with concept ----------------
// grid: NC blocks x 256 threads (thread == d in gather phase)
__global__ __launch_bounds__(256) void k_final(const float* __restrict__ candK,
                                               const int* __restrict__ candI,
                                               const float* __restrict__ X,
                                               const float* __restrict__ Cc,
                                               float* __restrict__ dots) {
  int j = blockIdx.x, tid = threadIdx.x;
  const int M = NBLK * KNN; // 320
  __shared__ float mk[M]; __shared__ int mi[M];
  __shared__ int topIdx[KNN];
  __shared__ float wvv[4]; __shared__ int wvi[4]; __shared__ int wvp[4];
  __shared__ float rsum[4];
  for (int e = tid; e < M; e += 256) { mk[e] = candK[(size_t)j * M + e]; mi[e] = candI[(size_t)j * M + e]; }
  __syncthreads();

  int lane = tid & 63, wv = tid >> 6;
  for (int rr = 0; rr < KNN; ++rr) {
    float v = 3.4e38f; int gi = 0x7fffffff; int pos = -1;
    for (int e = tid; e < M; e += 256) {
      if (mk[e] < v || (mk[e] == v && mi[e] < gi)) { v = mk[e]; gi = mi[e]; pos = e; }
    }
    #pragma unroll
    for (int off = 32; off; off >>= 1) {
      float ov = __shfl_xor(v, off); int ogi = __shfl_xor(gi, off); int op = __shfl_xor(pos, off);
      if (ov < v || (ov == v && ogi < gi)) { v = ov; gi = ogi; pos = op; }
    }
    if (lane == 0) { wvv[wv] = v; wvi[wv] = gi; wvp[wv] = pos; }
    __syncthreads();
    float bv = wvv[0]; int bgi = wvi[0]; int bpos = wvp[0];
    #pragma unroll
    for (int w = 1; w < 4; ++w) {
      if (wvv[w] < bv || (wvv[w] == bv && wvi[w] < bgi)) { bv = wvv[w]; bgi = wvi[w]; bpos = wvp[w]; }
    }
    if (tid == 0) { topIdx[rr] = bgi; mk[bpos] = 3.4e38f; }
    __syncthreads();
  }

  // gather + dot: thread == d
  float cj = Cc[tid * NC + j];
  float acc = 0.f;
  #pragma unroll
  for (int k = 0; k < KNN; ++k) acc += X[(size_t)topIdx[k] * D + tid] * cj;
  acc = wave_sum(acc);
  if (lane == 0) rsum[wv] = acc;
  __syncthreads();
  if (tid == 0) dots[j] = (rsum[0] + rsum[1] + rsum[2] + rsum[3]) * (1.0f / KNN);
}

// ---------------- final scalar: L_sparse_1 = mean(dots) ----------------
__global__ __launch_bounds__(64) void k_scal(const float* __restrict__ dots,
                                             float* __restrict__ out, int bs) {
  int lane = threadIdx.x;
  float v = (lane < NC) ? dots[lane] : 0.f;
  v = wave_sum(v);
  if (lane == 0) out[(size_t)2 * bs * NCLS] = v / (float)NC;
}

extern "C" void kernel_launch(void* const* d_in, const int* in_sizes, int n_in,
                              void* d_out, int out_size, void* d_ws, size_t ws_size,
                              hipStream_t stream) {
  const float* Xb = (const float*)d_in[0]; // train_embedding [bs][D]
  const float* XN = (const float*)d_in[1]; // train_embeddings [N][D]
  const float* C  = (const float*)d_in[2]; // concept [D][NC]
  const float* W  = (const float*)d_in[3]; // W_hx [D][NCLS]
  const float* bv = (const float*)d_in[4]; // b_hx [NCLS]
  float* out = (float*)d_out;

  int bs = in_sizes[0] / D;   // 4096
  int N  = in_sizes[1] / D;   // 200000

  float* w = (float*)d_ws;
  size_t offKey  = 0;
  size_t offGram = (size_t)NC * N;
  size_t offT1   = offGram + NC * NC;
  size_t offS    = offT1 + NC * NCLS;
  size_t offCK   = offS + NC * NCLS;
  size_t offCI   = offCK + (size_t)NC * NBLK * KNN;
  size_t offDots = offCI + (size_t)NC * NBLK * KNN;

  float* keyT  = w + offKey;
  float* gram  = w + offGram;
  float* T1    = w + offT1;
  float* S     = w + offS;
  float* candK = w + offCK;
  int*   candI = (int*)(w + offCI);
  float* dots  = w + offDots;

  // big memory-bound kernel first
  k_key<<<dim3((N + 255) / 256), dim3(256), 0, stream>>>(XN, C, keyT, N);
  k_gram<<<dim3(NC), dim3(256), 0, stream>>>(C, W, gram, T1);
  k_solve<<<dim3(1), dim3(256), 0, stream>>>(gram, T1, S, out, bs);
  k_pred<<<dim3(bs * SPLIT / 256), dim3(256), 0, stream>>>(Xb, C, W, bv, S, out, bs);
  k_topk<<<dim3(NBLK, NC), dim3(256), 0, stream>>>(keyT, candK, candI, N);
  k_final<<<dim3(NC), dim3(256), 0, stream>>>(candK, candI, XN, C, dots);
  k_scal<<<dim3(1), dim3(64), 0, stream>>>(dots, out, bs);
}